// Round 7
// baseline (157.283 us; speedup 1.0000x reference)
//
#include <hip/hip_runtime.h>
#include <hip/hip_bf16.h>

#define BB 16
#define NN 1024
#define CC 256

typedef __attribute__((ext_vector_type(8))) short bf16x8;
typedef __attribute__((ext_vector_type(4))) short s16x4;
typedef __attribute__((ext_vector_type(4))) float f32x4;

#define GPTR(p) ((const __attribute__((address_space(1))) void*)(p))
#define LPTR(p) ((__attribute__((address_space(3))) void*)(p))

__device__ __forceinline__ unsigned short f2bf(float f) {
  union { float f; unsigned u; } v; v.f = f;
  unsigned r = v.u + 0x7FFFu + ((v.u >> 16) & 1u);
  return (unsigned short)(r >> 16);
}

__device__ __forceinline__ bf16x8 pack8(f32x4 a, f32x4 b) {
  bf16x8 o;
  o[0] = (short)f2bf(a[0]); o[1] = (short)f2bf(a[1]);
  o[2] = (short)f2bf(a[2]); o[3] = (short)f2bf(a[3]);
  o[4] = (short)f2bf(b[0]); o[5] = (short)f2bf(b[1]);
  o[6] = (short)f2bf(b[2]); o[7] = (short)f2bf(b[3]);
  return o;
}

// Tiled GEMM: C[m][n] = sum_k A[m][k]*Bt[n][k]. BM=128 BN=64 BK=64.
// Double-buffered LDS + counted vmcnt + raw barriers (unchanged).
template <int BIAS_MODE, int F32OUT>
__global__ __launch_bounds__(256) void gemm_tile(
    const unsigned short* __restrict__ A, int lda, long sA,
    const unsigned short* __restrict__ Bt, int ldb, long sB,
    const float* __restrict__ bias,
    void* __restrict__ Out, int ldo, long sO, int K) {
  __shared__ unsigned short As[2][2 * 128 * 32];   // 2 x 16 KB
  __shared__ unsigned short Bs[2][2 * 64 * 32];    // 2 x 8 KB
  int b = blockIdx.x;
  int m0 = blockIdx.y * 128;
  int n0 = blockIdx.z * 64;
  int t = threadIdx.x;
  int w = t >> 6, lane = t & 63;
  int wm = (w >> 1) * 64, wn = (w & 1) * 32;
  int r = lane & 15, g = lane >> 4;

  const unsigned short* Ab = A + (long)b * sA;
  const unsigned short* Bb = Bt + (long)b * sB;

  int srow = t >> 2;
  int scol = (t & 3) * 8;

  f32x4 acc[4][2];
#pragma unroll
  for (int i = 0; i < 4; i++)
#pragma unroll
    for (int j = 0; j < 2; j++) acc[i][j] = (f32x4){0.f, 0.f, 0.f, 0.f};

#define STAGE_GT(buf, k0)                                                     \
  do {                                                                        \
    _Pragma("unroll") for (int kh = 0; kh < 2; kh++) {                        \
      _Pragma("unroll") for (int jj = 0; jj < 2; jj++) {                      \
        __builtin_amdgcn_global_load_lds(                                     \
            GPTR(Ab + (long)(m0 + srow + jj * 64) * lda + (k0) + kh * 32 +    \
                 scol),                                                       \
            LPTR(&As[buf][kh * 4096 + jj * 2048 + t * 8]), 16, 0, 0);         \
      }                                                                       \
      __builtin_amdgcn_global_load_lds(                                       \
          GPTR(Bb + (long)(n0 + srow) * ldb + (k0) + kh * 32 + scol),         \
          LPTR(&Bs[buf][kh * 2048 + t * 8]), 16, 0, 0);                       \
    }                                                                         \
  } while (0)

  int nt = K >> 6;
  STAGE_GT(0, 0);
  for (int tt = 0; tt < nt; ++tt) {
    int cb = tt & 1;
    if (tt < nt - 1) {
      STAGE_GT(cb ^ 1, (tt + 1) * 64);
      asm volatile("s_waitcnt vmcnt(6)" ::: "memory");
    } else {
      asm volatile("s_waitcnt vmcnt(0)" ::: "memory");
    }
    __builtin_amdgcn_sched_barrier(0);
    __builtin_amdgcn_s_barrier();          // all waves' current-buf DMA landed
    __builtin_amdgcn_sched_barrier(0);
#pragma unroll
    for (int kh = 0; kh < 2; kh++) {
      bf16x8 af[4], bfr[2];
#pragma unroll
      for (int ti = 0; ti < 4; ti++)
        af[ti] = *(const bf16x8*)&As[cb][kh * 4096 + (wm + ti * 16 + r) * 32 + g * 8];
#pragma unroll
      for (int tj = 0; tj < 2; tj++)
        bfr[tj] = *(const bf16x8*)&Bs[cb][kh * 2048 + (wn + tj * 16 + r) * 32 + g * 8];
#pragma unroll
      for (int ti = 0; ti < 4; ti++)
#pragma unroll
        for (int tj = 0; tj < 2; tj++)
          acc[ti][tj] = __builtin_amdgcn_mfma_f32_16x16x32_bf16(af[ti], bfr[tj], acc[ti][tj], 0, 0, 0);
    }
    __builtin_amdgcn_s_barrier();          // reads done before next overwrite
  }
#undef STAGE_GT

#pragma unroll
  for (int ti = 0; ti < 4; ti++) {
#pragma unroll
    for (int tj = 0; tj < 2; tj++) {
      int col = n0 + wn + tj * 16 + r;
      float bc = (BIAS_MODE == 1) ? bias[col] : 0.0f;
#pragma unroll
      for (int rr = 0; rr < 4; rr++) {
        int row = m0 + wm + ti * 16 + g * 4 + rr;
        float val = acc[ti][tj][rr] + bc;
        long oidx = (long)b * sO + (long)row * ldo + col;
        if (F32OUT)
          ((float*)Out)[oidx] = val;
        else
          ((unsigned short*)Out)[oidx] = f2bf(val);
      }
    }
  }
}

// Fused QKV projection with inline f32->bf16 conversion (unchanged).
__global__ __launch_bounds__(256) void gemm_qkv(
    const float* __restrict__ x,
    const float* __restrict__ Wq, const float* __restrict__ Wk,
    const float* __restrict__ Wv,
    const float* __restrict__ bq, const float* __restrict__ bk,
    const float* __restrict__ bv,
    const float* __restrict__ Wp,
    unsigned short* __restrict__ Qb, unsigned short* __restrict__ Kb,
    unsigned short* __restrict__ Vtb, unsigned short* __restrict__ Amat) {
  __shared__ unsigned short As[2 * 128 * 32];  // 16 KB
  __shared__ unsigned short Bs[2 * 128 * 32];  // 16 KB
  __shared__ float tile[32][33];               // transpose path only

  if (blockIdx.z == 6) {
    int id = blockIdx.x * 8 + blockIdx.y;      // 0..127
#pragma unroll 1
    for (int u = 0; u < 8; u++) {
      int wb = id * 8 + u;                     // 0..1023
      int h = wb >> 5;
      int n0w = (wb & 31) * 32;
#pragma unroll
      for (int j = 0; j < 4; j++) {
        int idx = threadIdx.x + j * 256;
        int a = idx >> 5, wc = idx & 31;
        tile[a][wc] = Wp[(size_t)h * (NN * 32) + (size_t)(n0w + a) * 32 + wc];
      }
      __syncthreads();
#pragma unroll
      for (int j = 0; j < 4; j++) {
        int idx = threadIdx.x + j * 256;
        int wc = idx >> 5, a = idx & 31;
        Amat[(size_t)(h * 32 + wc) * NN + n0w + a] = f2bf(tile[a][wc]);
      }
      __syncthreads();
    }
    return;
  }

  int b = blockIdx.x;
  int m0 = blockIdx.y * 128;
  int n0 = blockIdx.z * 128;
  int t = threadIdx.x;
  int w = t >> 6, lane = t & 63;
  int wm = (w >> 1) * 64, wn = (w & 1) * 64;
  int r = lane & 15, g = lane >> 4;

  const float* Ab = x + (long)b * NN * CC;
  int srow = t >> 2;            // 0..63
  int scol = (t & 3) * 8;

  const float* Wsel[2];
  int wrow[2];
#pragma unroll
  for (int jj = 0; jj < 2; jj++) {
    int nbase = n0 + jj * 64;
    int seg = nbase >> 8;
    Wsel[jj] = (seg == 0) ? Wq : (seg == 1 ? Wk : Wv);
    wrow[jj] = (nbase + srow) & 255;
  }

  f32x4 acc[4][4];
#pragma unroll
  for (int i = 0; i < 4; i++)
#pragma unroll
    for (int j = 0; j < 4; j++) acc[i][j] = (f32x4){0.f, 0.f, 0.f, 0.f};

  f32x4 pa[4][2], pw[4][2];
#pragma unroll
  for (int kh = 0; kh < 2; kh++)
#pragma unroll
    for (int jj = 0; jj < 2; jj++) {
      const float* asrc = Ab + (long)(m0 + srow + jj * 64) * CC + kh * 32 + scol;
      pa[kh * 2 + jj][0] = *(const f32x4*)asrc;
      pa[kh * 2 + jj][1] = *(const f32x4*)(asrc + 4);
      const float* wsrc = Wsel[jj] + (long)wrow[jj] * CC + kh * 32 + scol;
      pw[kh * 2 + jj][0] = *(const f32x4*)wsrc;
      pw[kh * 2 + jj][1] = *(const f32x4*)(wsrc + 4);
    }

  for (int k0 = 0; k0 < CC; k0 += 64) {
    if (k0) __builtin_amdgcn_s_barrier();   // prev compute's LDS reads done
#pragma unroll
    for (int kh = 0; kh < 2; kh++)
#pragma unroll
      for (int jj = 0; jj < 2; jj++) {
        *(bf16x8*)&As[kh * 4096 + jj * 2048 + t * 8] =
            pack8(pa[kh * 2 + jj][0], pa[kh * 2 + jj][1]);
        *(bf16x8*)&Bs[kh * 4096 + jj * 2048 + t * 8] =
            pack8(pw[kh * 2 + jj][0], pw[kh * 2 + jj][1]);
      }
    if (k0 < CC - 64) {
#pragma unroll
      for (int kh = 0; kh < 2; kh++)
#pragma unroll
        for (int jj = 0; jj < 2; jj++) {
          const float* asrc =
              Ab + (long)(m0 + srow + jj * 64) * CC + k0 + 64 + kh * 32 + scol;
          pa[kh * 2 + jj][0] = *(const f32x4*)asrc;
          pa[kh * 2 + jj][1] = *(const f32x4*)(asrc + 4);
          const float* wsrc =
              Wsel[jj] + (long)wrow[jj] * CC + k0 + 64 + kh * 32 + scol;
          pw[kh * 2 + jj][0] = *(const f32x4*)wsrc;
          pw[kh * 2 + jj][1] = *(const f32x4*)(wsrc + 4);
        }
    }
    asm volatile("s_waitcnt lgkmcnt(0)" ::: "memory");  // ds_writes visible
    __builtin_amdgcn_sched_barrier(0);
    __builtin_amdgcn_s_barrier();
    __builtin_amdgcn_sched_barrier(0);
#pragma unroll
    for (int kh = 0; kh < 2; kh++) {
      bf16x8 af[4], bfr[4];
#pragma unroll
      for (int ti = 0; ti < 4; ti++)
        af[ti] = *(const bf16x8*)&As[kh * 4096 + (wm + ti * 16 + r) * 32 + g * 8];
#pragma unroll
      for (int tj = 0; tj < 4; tj++)
        bfr[tj] = *(const bf16x8*)&Bs[kh * 4096 + (wn + tj * 16 + r) * 32 + g * 8];
#pragma unroll
      for (int ti = 0; ti < 4; ti++)
#pragma unroll
        for (int tj = 0; tj < 4; tj++)
          acc[ti][tj] = __builtin_amdgcn_mfma_f32_16x16x32_bf16(af[ti], bfr[tj], acc[ti][tj], 0, 0, 0);
    }
  }

  int sege = (n0 + wn) >> 8;
  const float* bsel = (sege == 0) ? bq : (sege == 1 ? bk : bv);
  int seg = n0 >> 8;
#pragma unroll
  for (int ti = 0; ti < 4; ti++) {
#pragma unroll
    for (int tj = 0; tj < 4; tj++) {
      int col = n0 + wn + tj * 16 + r;
      int c = col & 255;
      float bc = bsel[c];
#pragma unroll
      for (int rr = 0; rr < 4; rr++) {
        int row = m0 + wm + ti * 16 + g * 4 + rr;   // token index
        float val = acc[ti][tj][rr] + bc;
        long base = (long)b * NN * CC;
        if (seg == 0) {
          Qb[base + (long)row * CC + c] = f2bf(val);
        } else if (seg == 1) {
          Kb[base + ((long)(c >> 5) * NN + row) * 32 + (c & 31)] = f2bf(val);
        } else {
          Vtb[base + ((((long)(c >> 4) * 128 + (row >> 3)) * 16 + (c & 15)) * 8 + (row & 7))] = f2bf(val);
        }
      }
    }
  }
}

// Fused scores+softmax+PV v14. Same as v13 except phase 3 is latency-armored:
// v12 (8 waves) and v13 (16 waves) both measured 43.64 us — TLP-invariant,
// LDS-traffic-invariant => correlated latency stalls: all waves run identical
// barrier-synced 32-iter loops and stall on the same cycles (1-deep V load
// ~150cy slack < 200-400cy L2 latency; ar LDS reads 120cy exposed).
// v14: (1) per-wave ring start (w&7)*128 de-correlates loop phase across
// waves; (2) V prefetch 2-deep (issue j+2, hold j+1, use j); (3) ar (P-LDS)
// prefetch 1 iteration ahead. +24 VGPR, still <=128 for 4 waves/SIMD.
__global__ __launch_bounds__(1024, 4) void attn_fused(
    const unsigned short* __restrict__ Q,    // [B][1024][256]
    const unsigned short* __restrict__ Kt,   // [B][8][1024][32] tiled
    const unsigned short* __restrict__ Vt,   // [B] tiled V5
    unsigned short* __restrict__ QKVt) {     // [B][256][1024]
  __shared__ unsigned short ShBuf[64 * 1024];  // 128 KB: 2x64KB K slabs, then P[64][1024]
  __shared__ float red_m[64][20];              // [row][wave], padded stride 20
  __shared__ float red_s[64][20];
  int b = blockIdx.x;
  int n0 = blockIdx.y * 64;
  int t = threadIdx.x;
  int w = t >> 6, lane = t & 63;
  int r = lane & 15, g = lane >> 4;

  const unsigned short* kslab = Kt + (long)b * NN * CC;
  unsigned short* buf0 = &ShBuf[0];
  unsigned short* buf1 = &ShBuf[32 * 1024];

  // staging: wave w stages its 64 tokens x 32 ch (4KB) per slab, 4 instrs.
  // source pre-swizzled so LDS chan-group phys = (grp ^ (tok&3))  [rule #21]
  int stok = w * 64 + (lane >> 2);                    // + i*16
  int sgrp = (lane & 3) ^ ((lane >> 2) & 3);
  const unsigned short* ksrc0 = kslab + (long)stok * 32 + sgrp * 8;
  int dbase = (w * 64) * 32 + lane * 8;               // + i*512 elems

#pragma unroll
  for (int i = 0; i < 4; i++)
    __builtin_amdgcn_global_load_lds(GPTR(ksrc0 + i * 512),
                                     LPTR(&buf0[dbase + i * 512]), 16, 0, 0);

  const unsigned short* qbase = Q + ((long)b * NN + n0 + r) * CC + g * 8;
  bf16x8 qa[4];
#pragma unroll
  for (int rt = 0; rt < 4; rt++)
    qa[rt] = *(const bf16x8*)(qbase + rt * 16 * CC);

  f32x4 acc[4][4];
#pragma unroll
  for (int i = 0; i < 4; i++)
#pragma unroll
    for (int j = 0; j < 4; j++) acc[i][j] = (f32x4){0.f, 0.f, 0.f, 0.f};

  int kgrp = (g ^ (r & 3)) * 8;   // swizzled chan-group for kf reads
#pragma unroll
  for (int kk = 0; kk < 8; kk++) {
    unsigned short* cur = (kk & 1) ? buf1 : buf0;
    unsigned short* nxt = (kk & 1) ? buf0 : buf1;
    if (kk < 7) {
      const unsigned short* src = ksrc0 + (long)(kk + 1) * (NN * 32);
#pragma unroll
      for (int i = 0; i < 4; i++)
        __builtin_amdgcn_global_load_lds(GPTR(src + i * 512),
                                         LPTR(&nxt[dbase + i * 512]), 16, 0, 0);
      asm volatile("s_waitcnt vmcnt(4)" ::: "memory");  // slab kk landed
    } else {
      asm volatile("s_waitcnt vmcnt(0)" ::: "memory");
    }
    __builtin_amdgcn_sched_barrier(0);
    bf16x8 qn[4];
    if (kk < 7) {
#pragma unroll
      for (int rt = 0; rt < 4; rt++)
        qn[rt] = *(const bf16x8*)(qbase + (kk + 1) * 32 + rt * 16 * CC);
    }
    __builtin_amdgcn_s_setprio(1);
#pragma unroll
    for (int ct = 0; ct < 4; ct++) {
      bf16x8 kf = *(const bf16x8*)&cur[(w * 64 + ct * 16 + r) * 32 + kgrp];
#pragma unroll
      for (int rt = 0; rt < 4; rt++)
        acc[rt][ct] = __builtin_amdgcn_mfma_f32_16x16x32_bf16(kf, qa[rt], acc[rt][ct], 0, 0, 0);
    }
    __builtin_amdgcn_s_setprio(0);
    if (kk < 7) {
#pragma unroll
      for (int rt = 0; rt < 4; rt++) qa[rt] = qn[rt];
    }
    __builtin_amdgcn_sched_barrier(0);
  }

  // phase-3 ring start (de-correlated across waves) + 2-deep V prefetch;
  // issued here so the L2 latency hides under softmax.
  const unsigned short* vbase = Vt + (long)b * NN * CC;  // tiled V5
  int mstart = (w & 7) * 128;
  bf16x8 brp0 = *(const bf16x8*)(
      vbase + (((long)w * 128 + (mstart >> 3) + g) * 16 + r) * 8);
  bf16x8 brp1 = *(const bf16x8*)(
      vbase + (((long)w * 128 + (((mstart + 32) & 1023) >> 3) + g) * 16 + r) * 8);
  __builtin_amdgcn_sched_barrier(0);

  // ---- softmax ----  row q = rt*16 + r (per lane), tokens ct*16+g*4+rr
  float mrow[4];
#pragma unroll
  for (int rt = 0; rt < 4; rt++) {
    float m = acc[rt][0][0];
#pragma unroll
    for (int ct = 0; ct < 4; ct++)
#pragma unroll
      for (int rr = 0; rr < 4; rr++) m = fmaxf(m, acc[rt][ct][rr]);
    m = fmaxf(m, __shfl_xor(m, 16, 64));
    m = fmaxf(m, __shfl_xor(m, 32, 64));
    mrow[rt] = m;
  }
  if (lane < 16) {
#pragma unroll
    for (int rt = 0; rt < 4; rt++) red_m[rt * 16 + lane][w] = mrow[rt];
  }
  __syncthreads();   // #1: red_m complete; also orders all K-buffer reads
#pragma unroll
  for (int rt = 0; rt < 4; rt++) {
    int row = rt * 16 + r;
    f32x4 a = *(const f32x4*)&red_m[row][0];
    f32x4 bq4 = *(const f32x4*)&red_m[row][4];
    f32x4 c = *(const f32x4*)&red_m[row][8];
    f32x4 d = *(const f32x4*)&red_m[row][12];
    float m = fmaxf(fmaxf(fmaxf(a[0], a[1]), fmaxf(a[2], a[3])),
                    fmaxf(fmaxf(bq4[0], bq4[1]), fmaxf(bq4[2], bq4[3])));
    m = fmaxf(m, fmaxf(fmaxf(fmaxf(c[0], c[1]), fmaxf(c[2], c[3])),
                       fmaxf(fmaxf(d[0], d[1]), fmaxf(d[2], d[3]))));
    mrow[rt] = m;
  }
  float ssum[4];
#pragma unroll
  for (int rt = 0; rt < 4; rt++) {
    float s = 0.f;
#pragma unroll
    for (int ct = 0; ct < 4; ct++)
#pragma unroll
      for (int rr = 0; rr < 4; rr++) {
        float e = exp2f((acc[rt][ct][rr] - mrow[rt]) * 1.44269504088896f);
        acc[rt][ct][rr] = e;
        s += e;
      }
    s += __shfl_xor(s, 16, 64);
    s += __shfl_xor(s, 32, 64);
    ssum[rt] = s;
  }
  if (lane < 16) {
#pragma unroll
    for (int rt = 0; rt < 4; rt++) red_s[rt * 16 + lane][w] = ssum[rt];
  }
  __syncthreads();   // #2
  // ---- P -> LDS (overlays K buffers), b64 writes, chunk-XOR swizzle ----
#pragma unroll
  for (int rt = 0; rt < 4; rt++) {
    int prow = rt * 16 + r;
    f32x4 a = *(const f32x4*)&red_s[prow][0];
    f32x4 bq4 = *(const f32x4*)&red_s[prow][4];
    f32x4 c = *(const f32x4*)&red_s[prow][8];
    f32x4 d = *(const f32x4*)&red_s[prow][12];
    float s = (a[0] + a[1] + a[2] + a[3]) + (bq4[0] + bq4[1] + bq4[2] + bq4[3]) +
              (c[0] + c[1] + c[2] + c[3]) + (d[0] + d[1] + d[2] + d[3]);
    float inv = 1.0f / s;
    int sw = prow & 7;
#pragma unroll
    for (int ct = 0; ct < 4; ct++) {
      int col = w * 64 + ct * 16 + g * 4;           // 4 consecutive tokens
      int chunk = (col >> 3) ^ sw;
      s16x4 pk;
      pk.x = (short)f2bf(acc[rt][ct][0] * inv);
      pk.y = (short)f2bf(acc[rt][ct][1] * inv);
      pk.z = (short)f2bf(acc[rt][ct][2] * inv);
      pk.w = (short)f2bf(acc[rt][ct][3] * inv);
      *(s16x4*)&ShBuf[prow * 1024 + chunk * 8 + (col & 7)] = pk;
    }
  }
  __syncthreads();   // #3

  // ---- phase 3: O = P V.  Wave w owns O cols [w*16,+16), rows n0..n0+64.
  // Ring order from mstart; ar prefetched 1 iter ahead, V 2 deep.
  f32x4 o[4];
#pragma unroll
  for (int i = 0; i < 4; i++) o[i] = (f32x4){0.f, 0.f, 0.f, 0.f};

  bf16x8 arp[4];
#pragma unroll
  for (int rt = 0; rt < 4; rt++) {
    int prow = rt * 16 + r;
    int chunk = ((mstart >> 3) + g) ^ (prow & 7);
    arp[rt] = *(const bf16x8*)&ShBuf[prow * 1024 + chunk * 8];
  }

#pragma unroll 4
  for (int j = 0; j < 32; j++) {
    int m1 = (mstart + (j + 1) * 32) & 1023;
    int m2 = (mstart + (j + 2) * 32) & 1023;
    bf16x8 ar[4];
#pragma unroll
    for (int rt = 0; rt < 4; rt++) ar[rt] = arp[rt];
    bf16x8 br = brp0;
    brp0 = brp1;
    if (j < 30)
      brp1 = *(const bf16x8*)(
          vbase + (((long)w * 128 + (m2 >> 3) + g) * 16 + r) * 8);
    if (j < 31) {
#pragma unroll
      for (int rt = 0; rt < 4; rt++) {
        int prow = rt * 16 + r;
        int chunk = ((m1 >> 3) + g) ^ (prow & 7);
        arp[rt] = *(const bf16x8*)&ShBuf[prow * 1024 + chunk * 8];
      }
    }
    __builtin_amdgcn_s_setprio(1);
#pragma unroll
    for (int rt = 0; rt < 4; rt++)
      o[rt] = __builtin_amdgcn_mfma_f32_16x16x32_bf16(ar[rt], br, o[rt], 0, 0, 0);
    __builtin_amdgcn_s_setprio(0);
  }

  // ---- epilogue: direct packed stores; block covers full 128B line per c ----
  unsigned short* obase = QKVt + (long)b * NN * CC;
  int c = w * 16 + r;
#pragma unroll
  for (int rt = 0; rt < 4; rt++) {
    int n = n0 + rt * 16 + g * 4;
    s16x4 pk;
    pk.x = (short)f2bf(o[rt][0]);
    pk.y = (short)f2bf(o[rt][1]);
    pk.z = (short)f2bf(o[rt][2]);
    pk.w = (short)f2bf(o[rt][3]);
    *(s16x4*)(obase + (long)c * NN + n) = pk;
  }
}

extern "C" void kernel_launch(void* const* d_in, const int* in_sizes, int n_in,
                              void* d_out, int out_size, void* d_ws, size_t ws_size,
                              hipStream_t stream) {
  const float* x  = (const float*)d_in[0];
  const float* Wq = (const float*)d_in[1];
  const float* bq = (const float*)d_in[2];
  const float* Wk = (const float*)d_in[3];
  const float* bk = (const float*)d_in[4];
  const float* Wv = (const float*)d_in[5];
  const float* bv = (const float*)d_in[6];
  const float* Wp = (const float*)d_in[7];
  float* out = (float*)d_out;

  const long BNC = (long)BB * NN * CC;

  char* p = (char*)d_ws;
  unsigned short* Amat  = (unsigned short*)p; p += (long)NN * NN * 2;
  unsigned short* Qb    = (unsigned short*)p; p += BNC * 2;
  unsigned short* Ktb   = (unsigned short*)p; p += BNC * 2;   // tiled Kt
  unsigned short* Vtb   = (unsigned short*)p; p += BNC * 2;   // tiled V5
  unsigned short* QKVt  = (unsigned short*)p; p += BNC * 2;   // [b][c][n]

  // Fused QKV projection (inline f32->bf16) + Wp transpose (z==6 slice)
  gemm_qkv<<<dim3(BB, 8, 7), 256, 0, stream>>>(
      x, Wq, Wk, Wv, bq, bk, bv, Wp, Qb, Ktb, Vtb, Amat);

  // Fused softmax(QK^T)·V -> QKVt[c][n];  64 rows/block, 16 waves, 1 block/CU
  attn_fused<<<dim3(BB, NN / 64), 1024, 0, stream>>>(Qb, Ktb, Vtb, QKVt);

  // Z[hw][c] = sum_n Amat[hw][n] * QKVt[c][n] : M=1024, N=256, K=1024, f32 out
  gemm_tile<0, 1><<<dim3(BB, 8, 4), 256, 0, stream>>>(
      Amat, NN, 0L, QKVt, NN, (long)NN * CC, nullptr,
      out, CC, (long)NN * CC, NN);
}

// Round 8
// 149.591 us; speedup vs baseline: 1.0514x; 1.0514x over previous
//
#include <hip/hip_runtime.h>
#include <hip/hip_bf16.h>

#define BB 16
#define NN 1024
#define CC 256

typedef __attribute__((ext_vector_type(8))) short bf16x8;
typedef __attribute__((ext_vector_type(4))) short s16x4;
typedef __attribute__((ext_vector_type(4))) float f32x4;

#define GPTR(p) ((const __attribute__((address_space(1))) void*)(p))
#define LPTR(p) ((__attribute__((address_space(3))) void*)(p))

__device__ __forceinline__ unsigned short f2bf(float f) {
  union { float f; unsigned u; } v; v.f = f;
  unsigned r = v.u + 0x7FFFu + ((v.u >> 16) & 1u);
  return (unsigned short)(r >> 16);
}

__device__ __forceinline__ bf16x8 pack8(f32x4 a, f32x4 b) {
  bf16x8 o;
  o[0] = (short)f2bf(a[0]); o[1] = (short)f2bf(a[1]);
  o[2] = (short)f2bf(a[2]); o[3] = (short)f2bf(a[3]);
  o[4] = (short)f2bf(b[0]); o[5] = (short)f2bf(b[1]);
  o[6] = (short)f2bf(b[2]); o[7] = (short)f2bf(b[3]);
  return o;
}

// Tiled GEMM: C[m][n] = sum_k A[m][k]*Bt[n][k]. BM=128 BN=64 BK=64.
// Double-buffered LDS + counted vmcnt + raw barriers.
// r8: chunk-XOR LDS swizzle via pre-swizzled GLOBAL source (rule #21:
// global_load_lds dest must stay lane-linear). Logical k-chunk c of row R
// lands at phys chunk c^(R&3); fragment reads use (g^(r&3)) -> 8-way LDS
// read conflict becomes 2-way.
template <int BIAS_MODE, int F32OUT>
__global__ __launch_bounds__(256) void gemm_tile(
    const unsigned short* __restrict__ A, int lda, long sA,
    const unsigned short* __restrict__ Bt, int ldb, long sB,
    const float* __restrict__ bias,
    void* __restrict__ Out, int ldo, long sO, int K) {
  __shared__ unsigned short As[2][2 * 128 * 32];   // 2 x 16 KB
  __shared__ unsigned short Bs[2][2 * 64 * 32];    // 2 x 8 KB
  int b = blockIdx.x;
  int m0 = blockIdx.y * 128;
  int n0 = blockIdx.z * 64;
  int t = threadIdx.x;
  int w = t >> 6, lane = t & 63;
  int wm = (w >> 1) * 64, wn = (w & 1) * 32;
  int r = lane & 15, g = lane >> 4;

  const unsigned short* Ab = A + (long)b * sA;
  const unsigned short* Bb = Bt + (long)b * sB;

  int srow = t >> 2;
  int scolsw = (((t & 3) ^ ((t >> 2) & 3))) * 8;   // pre-swizzled source chunk
  int ag = ((g ^ (r & 3))) * 8;                    // swizzled read chunk

  f32x4 acc[4][2];
#pragma unroll
  for (int i = 0; i < 4; i++)
#pragma unroll
    for (int j = 0; j < 2; j++) acc[i][j] = (f32x4){0.f, 0.f, 0.f, 0.f};

#define STAGE_GT(buf, k0)                                                     \
  do {                                                                        \
    _Pragma("unroll") for (int kh = 0; kh < 2; kh++) {                        \
      _Pragma("unroll") for (int jj = 0; jj < 2; jj++) {                      \
        __builtin_amdgcn_global_load_lds(                                     \
            GPTR(Ab + (long)(m0 + srow + jj * 64) * lda + (k0) + kh * 32 +    \
                 scolsw),                                                     \
            LPTR(&As[buf][kh * 4096 + jj * 2048 + t * 8]), 16, 0, 0);         \
      }                                                                       \
      __builtin_amdgcn_global_load_lds(                                       \
          GPTR(Bb + (long)(n0 + srow) * ldb + (k0) + kh * 32 + scolsw),       \
          LPTR(&Bs[buf][kh * 2048 + t * 8]), 16, 0, 0);                       \
    }                                                                         \
  } while (0)

  int nt = K >> 6;
  STAGE_GT(0, 0);
  for (int tt = 0; tt < nt; ++tt) {
    int cb = tt & 1;
    if (tt < nt - 1) {
      STAGE_GT(cb ^ 1, (tt + 1) * 64);
      asm volatile("s_waitcnt vmcnt(6)" ::: "memory");
    } else {
      asm volatile("s_waitcnt vmcnt(0)" ::: "memory");
    }
    __builtin_amdgcn_sched_barrier(0);
    __builtin_amdgcn_s_barrier();          // all waves' current-buf DMA landed
    __builtin_amdgcn_sched_barrier(0);
#pragma unroll
    for (int kh = 0; kh < 2; kh++) {
      bf16x8 af[4], bfr[2];
#pragma unroll
      for (int ti = 0; ti < 4; ti++)
        af[ti] = *(const bf16x8*)&As[cb][kh * 4096 + (wm + ti * 16 + r) * 32 + ag];
#pragma unroll
      for (int tj = 0; tj < 2; tj++)
        bfr[tj] = *(const bf16x8*)&Bs[cb][kh * 2048 + (wn + tj * 16 + r) * 32 + ag];
#pragma unroll
      for (int ti = 0; ti < 4; ti++)
#pragma unroll
        for (int tj = 0; tj < 2; tj++)
          acc[ti][tj] = __builtin_amdgcn_mfma_f32_16x16x32_bf16(af[ti], bfr[tj], acc[ti][tj], 0, 0, 0);
    }
    __builtin_amdgcn_s_barrier();          // reads done before next overwrite
  }
#undef STAGE_GT

#pragma unroll
  for (int ti = 0; ti < 4; ti++) {
#pragma unroll
    for (int tj = 0; tj < 2; tj++) {
      int col = n0 + wn + tj * 16 + r;
      float bc = (BIAS_MODE == 1) ? bias[col] : 0.0f;
#pragma unroll
      for (int rr = 0; rr < 4; rr++) {
        int row = m0 + wm + ti * 16 + g * 4 + rr;
        float val = acc[ti][tj][rr] + bc;
        long oidx = (long)b * sO + (long)row * ldo + col;
        if (F32OUT)
          ((float*)Out)[oidx] = val;
        else
          ((unsigned short*)Out)[oidx] = f2bf(val);
      }
    }
  }
}

// Fused QKV projection with inline f32->bf16 conversion.
// r8: reg-staged path gets store-side chunk-XOR swizzle (phys chunk =
// c^(srow&3)), reads use (g^(r&3)) — kills the 786K 8-way LDS read conflict
// seen in r7's profile. Transpose tile overlays As (LDS 37->33 KB).
__global__ __launch_bounds__(256) void gemm_qkv(
    const float* __restrict__ x,
    const float* __restrict__ Wq, const float* __restrict__ Wk,
    const float* __restrict__ Wv,
    const float* __restrict__ bq, const float* __restrict__ bk,
    const float* __restrict__ bv,
    const float* __restrict__ Wp,
    unsigned short* __restrict__ Qb, unsigned short* __restrict__ Kb,
    unsigned short* __restrict__ Vtb, unsigned short* __restrict__ Amat) {
  __shared__ unsigned short As[2 * 128 * 32];  // 16 KB (also transpose tile)
  __shared__ unsigned short Bs[2 * 128 * 32];  // 16 KB

  if (blockIdx.z == 6) {
    // ---- Wp transpose: Amat[h*32+w][n] = Wp[h][n][w], bf16 ----
    float* tile = (float*)As;                  // [32][33] overlay
    int id = blockIdx.x * 8 + blockIdx.y;      // 0..127
#pragma unroll 1
    for (int u = 0; u < 8; u++) {
      int wb = id * 8 + u;                     // 0..1023
      int h = wb >> 5;
      int n0w = (wb & 31) * 32;
#pragma unroll
      for (int j = 0; j < 4; j++) {
        int idx = threadIdx.x + j * 256;
        int a = idx >> 5, wc = idx & 31;
        tile[a * 33 + wc] = Wp[(size_t)h * (NN * 32) + (size_t)(n0w + a) * 32 + wc];
      }
      __syncthreads();
#pragma unroll
      for (int j = 0; j < 4; j++) {
        int idx = threadIdx.x + j * 256;
        int wc = idx >> 5, a = idx & 31;
        Amat[(size_t)(h * 32 + wc) * NN + n0w + a] = f2bf(tile[a * 33 + wc]);
      }
      __syncthreads();
    }
    return;
  }

  int b = blockIdx.x;
  int m0 = blockIdx.y * 128;
  int n0 = blockIdx.z * 128;
  int t = threadIdx.x;
  int w = t >> 6, lane = t & 63;
  int wm = (w >> 1) * 64, wn = (w & 1) * 64;
  int r = lane & 15, g = lane >> 4;

  const float* Ab = x + (long)b * NN * CC;
  int srow = t >> 2;            // 0..63
  int scol = (t & 3) * 8;
  // store-side swizzle: data for logical chunk (t&3) goes to phys (t&3)^(srow&3)
  int sb = srow * 32 + (((t & 3) ^ (srow & 3)) * 8);
  int ag = ((g ^ (r & 3))) * 8; // swizzled read chunk

  const float* Wsel[2];
  int wrow[2];
#pragma unroll
  for (int jj = 0; jj < 2; jj++) {
    int nbase = n0 + jj * 64;
    int seg = nbase >> 8;
    Wsel[jj] = (seg == 0) ? Wq : (seg == 1 ? Wk : Wv);
    wrow[jj] = (nbase + srow) & 255;
  }

  f32x4 acc[4][4];
#pragma unroll
  for (int i = 0; i < 4; i++)
#pragma unroll
    for (int j = 0; j < 4; j++) acc[i][j] = (f32x4){0.f, 0.f, 0.f, 0.f};

  f32x4 pa[4][2], pw[4][2];
#pragma unroll
  for (int kh = 0; kh < 2; kh++)
#pragma unroll
    for (int jj = 0; jj < 2; jj++) {
      const float* asrc = Ab + (long)(m0 + srow + jj * 64) * CC + kh * 32 + scol;
      pa[kh * 2 + jj][0] = *(const f32x4*)asrc;
      pa[kh * 2 + jj][1] = *(const f32x4*)(asrc + 4);
      const float* wsrc = Wsel[jj] + (long)wrow[jj] * CC + kh * 32 + scol;
      pw[kh * 2 + jj][0] = *(const f32x4*)wsrc;
      pw[kh * 2 + jj][1] = *(const f32x4*)(wsrc + 4);
    }

  for (int k0 = 0; k0 < CC; k0 += 64) {
    if (k0) __builtin_amdgcn_s_barrier();   // prev compute's LDS reads done
#pragma unroll
    for (int kh = 0; kh < 2; kh++)
#pragma unroll
      for (int jj = 0; jj < 2; jj++) {
        *(bf16x8*)&As[kh * 4096 + jj * 2048 + sb] =
            pack8(pa[kh * 2 + jj][0], pa[kh * 2 + jj][1]);
        *(bf16x8*)&Bs[kh * 4096 + jj * 2048 + sb] =
            pack8(pw[kh * 2 + jj][0], pw[kh * 2 + jj][1]);
      }
    if (k0 < CC - 64) {
#pragma unroll
      for (int kh = 0; kh < 2; kh++)
#pragma unroll
        for (int jj = 0; jj < 2; jj++) {
          const float* asrc =
              Ab + (long)(m0 + srow + jj * 64) * CC + k0 + 64 + kh * 32 + scol;
          pa[kh * 2 + jj][0] = *(const f32x4*)asrc;
          pa[kh * 2 + jj][1] = *(const f32x4*)(asrc + 4);
          const float* wsrc =
              Wsel[jj] + (long)wrow[jj] * CC + k0 + 64 + kh * 32 + scol;
          pw[kh * 2 + jj][0] = *(const f32x4*)wsrc;
          pw[kh * 2 + jj][1] = *(const f32x4*)(wsrc + 4);
        }
    }
    asm volatile("s_waitcnt lgkmcnt(0)" ::: "memory");  // ds_writes visible
    __builtin_amdgcn_sched_barrier(0);
    __builtin_amdgcn_s_barrier();
    __builtin_amdgcn_sched_barrier(0);
#pragma unroll
    for (int kh = 0; kh < 2; kh++) {
      bf16x8 af[4], bfr[4];
#pragma unroll
      for (int ti = 0; ti < 4; ti++)
        af[ti] = *(const bf16x8*)&As[kh * 4096 + (wm + ti * 16 + r) * 32 + ag];
#pragma unroll
      for (int tj = 0; tj < 4; tj++)
        bfr[tj] = *(const bf16x8*)&Bs[kh * 4096 + (wn + tj * 16 + r) * 32 + ag];
#pragma unroll
      for (int ti = 0; ti < 4; ti++)
#pragma unroll
        for (int tj = 0; tj < 4; tj++)
          acc[ti][tj] = __builtin_amdgcn_mfma_f32_16x16x32_bf16(af[ti], bfr[tj], acc[ti][tj], 0, 0, 0);
    }
  }

  int sege = (n0 + wn) >> 8;
  const float* bsel = (sege == 0) ? bq : (sege == 1 ? bk : bv);
  int seg = n0 >> 8;
#pragma unroll
  for (int ti = 0; ti < 4; ti++) {
#pragma unroll
    for (int tj = 0; tj < 4; tj++) {
      int col = n0 + wn + tj * 16 + r;
      int c = col & 255;
      float bc = bsel[c];
#pragma unroll
      for (int rr = 0; rr < 4; rr++) {
        int row = m0 + wm + ti * 16 + g * 4 + rr;   // token index
        float val = acc[ti][tj][rr] + bc;
        long base = (long)b * NN * CC;
        if (seg == 0) {
          Qb[base + (long)row * CC + c] = f2bf(val);
        } else if (seg == 1) {
          Kb[base + ((long)(c >> 5) * NN + row) * 32 + (c & 31)] = f2bf(val);
        } else {
          Vtb[base + ((((long)(c >> 4) * 128 + (row >> 3)) * 16 + (c & 15)) * 8 + (row & 7))] = f2bf(val);
        }
      }
    }
  }
}

// Fused scores+softmax+PV v12 (r5-exact revert — best measured total 149.9).
// 512 thr = 8 waves; 64 Q-rows/block; grid (batch,16) = 1 block/CU, XCD b%8.
// Phase 1: barrier-free per-wave double-buffered DMA, counted vmcnt(8),
// setprio around MFMA. Phase 3: 1-deep V register pipeline, first V frags
// issued before softmax.
__global__ __launch_bounds__(512, 2) void attn_fused(
    const unsigned short* __restrict__ Q,    // [B][1024][256]
    const unsigned short* __restrict__ Kt,   // [B][8][1024][32] tiled
    const unsigned short* __restrict__ Vt,   // [B] tiled V5
    unsigned short* __restrict__ QKVt) {     // [B][256][1024]
  __shared__ unsigned short ShBuf[64 * 1024];  // 128 KB: 2x64KB K slabs, then P[64][1024]
  __shared__ float red[8][64];
  int b = blockIdx.x;
  int n0 = blockIdx.y * 64;
  int t = threadIdx.x;
  int w = t >> 6, lane = t & 63;
  int r = lane & 15, g = lane >> 4;

  // wave-private K slice: tokens [w*128, +128), 32 ch per slab, 8 KB
  const unsigned short* kslab = Kt + (long)b * NN * CC + w * 128 * 32;
  unsigned short* wbuf0 = &ShBuf[w * 4096];           // 8 KB slice in buffer 0
  unsigned short* wbuf1 = &ShBuf[32768 + w * 4096];   // 8 KB slice in buffer 1

  const unsigned short* qbase = Q + ((long)b * NN + n0 + r) * CC + g * 8;

  // prologue: stage slab 0 (own slice), load q-frags slab 0
#pragma unroll
  for (int j = 0; j < 8; j++)
    __builtin_amdgcn_global_load_lds(GPTR(kslab + j * 512 + lane * 8),
                                     LPTR(wbuf0 + j * 512 + lane * 8), 16, 0, 0);
  bf16x8 qa[4];
#pragma unroll
  for (int rt = 0; rt < 4; rt++)
    qa[rt] = *(const bf16x8*)(qbase + rt * 16 * CC);

  f32x4 acc[4][8];
#pragma unroll
  for (int i = 0; i < 4; i++)
#pragma unroll
    for (int j = 0; j < 8; j++) acc[i][j] = (f32x4){0.f, 0.f, 0.f, 0.f};

#pragma unroll
  for (int kk = 0; kk < 8; kk++) {
    unsigned short* cur = (kk & 1) ? wbuf1 : wbuf0;
    unsigned short* nxt = (kk & 1) ? wbuf0 : wbuf1;
    if (kk < 7) {
      const unsigned short* src = kslab + (long)(kk + 1) * (NN * 32);
#pragma unroll
      for (int j = 0; j < 8; j++)
        __builtin_amdgcn_global_load_lds(GPTR(src + j * 512 + lane * 8),
                                         LPTR(nxt + j * 512 + lane * 8), 16, 0, 0);
      asm volatile("s_waitcnt vmcnt(8)" ::: "memory");  // slab kk landed; kk+1 in flight
    } else {
      asm volatile("s_waitcnt vmcnt(0)" ::: "memory");
    }
    __builtin_amdgcn_sched_barrier(0);
    bf16x8 qn[4];
    if (kk < 7) {
#pragma unroll
      for (int rt = 0; rt < 4; rt++)
        qn[rt] = *(const bf16x8*)(qbase + (kk + 1) * 32 + rt * 16 * CC);
    }
    __builtin_amdgcn_s_setprio(1);
#pragma unroll
    for (int ct = 0; ct < 8; ct++) {
      bf16x8 kf = *(const bf16x8*)&cur[(ct * 16 + r) * 32 + g * 8];
#pragma unroll
      for (int rt = 0; rt < 4; rt++)
        acc[rt][ct] = __builtin_amdgcn_mfma_f32_16x16x32_bf16(qa[rt], kf, acc[rt][ct], 0, 0, 0);
    }
    __builtin_amdgcn_s_setprio(0);
    if (kk < 7) {
#pragma unroll
      for (int rt = 0; rt < 4; rt++) qa[rt] = qn[rt];
    }
    __builtin_amdgcn_sched_barrier(0);  // pin cross-iteration order (stage vs prior reads)
  }

  // prefetch first V fragments (phase 3, m0=0) — latency hides under softmax
  const unsigned short* vbase = Vt + (long)b * NN * CC;  // tiled V5
  int cw = w * 32;
  bf16x8 brp[2];
#pragma unroll
  for (int bt = 0; bt < 2; bt++) {
    long vidx = (((long)((cw >> 4) + bt) * 128 + g) * 16 + r) * 8;
    brp[bt] = *(const bf16x8*)(vbase + vidx);
  }
  __builtin_amdgcn_sched_barrier(0);

  // ---- softmax ----  acc[rt][ct][rr]: row = rt*16+g*4+rr, col = w*128+ct*16+r
  float mrow[4][4];
#pragma unroll
  for (int rt = 0; rt < 4; rt++) {
#pragma unroll
    for (int rr = 0; rr < 4; rr++) {
      float m = acc[rt][0][rr];
#pragma unroll
      for (int ct = 1; ct < 8; ct++) m = fmaxf(m, acc[rt][ct][rr]);
#pragma unroll
      for (int d = 1; d < 16; d <<= 1) m = fmaxf(m, __shfl_xor(m, d, 64));
      mrow[rt][rr] = m;
    }
  }
  if (r == 0) {
#pragma unroll
    for (int rt = 0; rt < 4; rt++)
#pragma unroll
      for (int rr = 0; rr < 4; rr++)
        red[w][rt * 16 + g * 4 + rr] = mrow[rt][rr];
  }
  __syncthreads();   // #1: also orders all phase-1 K reads before P writes below
#pragma unroll
  for (int rt = 0; rt < 4; rt++) {
#pragma unroll
    for (int rr = 0; rr < 4; rr++) {
      int row = rt * 16 + g * 4 + rr;
      float m = red[0][row];
#pragma unroll
      for (int w2 = 1; w2 < 8; w2++) m = fmaxf(m, red[w2][row]);
      mrow[rt][rr] = m;
    }
  }
  __syncthreads();   // #2: WAR before sum overwrites red
  float ssum[4][4];
#pragma unroll
  for (int rt = 0; rt < 4; rt++) {
#pragma unroll
    for (int rr = 0; rr < 4; rr++) {
      float s = 0.f;
#pragma unroll
      for (int ct = 0; ct < 8; ct++) {
        float e = exp2f((acc[rt][ct][rr] - mrow[rt][rr]) * 1.44269504088896f);
        acc[rt][ct][rr] = e;
        s += e;
      }
#pragma unroll
      for (int d = 1; d < 16; d <<= 1) s += __shfl_xor(s, d, 64);
      ssum[rt][rr] = s;
    }
  }
  if (r == 0) {
#pragma unroll
    for (int rt = 0; rt < 4; rt++)
#pragma unroll
      for (int rr = 0; rr < 4; rr++)
        red[w][rt * 16 + g * 4 + rr] = ssum[rt][rr];
  }
  __syncthreads();   // #3
  // ---- phase 2: P -> LDS (overlays K buffers), chunk-XOR swizzle (prow&7) ----
#pragma unroll
  for (int rt = 0; rt < 4; rt++) {
#pragma unroll
    for (int rr = 0; rr < 4; rr++) {
      int prow = rt * 16 + g * 4 + rr;
      float s = 0.f;
#pragma unroll
      for (int w2 = 0; w2 < 8; w2++) s += red[w2][prow];
      float inv = 1.0f / s;
      int sw = prow & 7;
#pragma unroll
      for (int ct = 0; ct < 8; ct++) {
        int col = w * 128 + ct * 16 + r;
        int chunk = (col >> 3) ^ sw;
        ShBuf[prow * 1024 + chunk * 8 + (col & 7)] = f2bf(acc[rt][ct][rr] * inv);
      }
    }
  }
  __syncthreads();   // #4

  // ---- phase 3: O = P V.  Wave w owns O cols [w*32,+32), rows n0..n0+64.
  f32x4 o[4][2];
#pragma unroll
  for (int i = 0; i < 4; i++)
#pragma unroll
    for (int j = 0; j < 2; j++) o[i][j] = (f32x4){0.f, 0.f, 0.f, 0.f};

#pragma unroll 4
  for (int m0 = 0; m0 < NN; m0 += 32) {
    bf16x8 ar[4], br[2];
    br[0] = brp[0]; br[1] = brp[1];
    if (m0 + 32 < NN) {
#pragma unroll
      for (int bt = 0; bt < 2; bt++) {
        long vidx = (((long)((cw >> 4) + bt) * 128 + ((m0 + 32) >> 3) + g) * 16 + r) * 8;
        brp[bt] = *(const bf16x8*)(vbase + vidx);
      }
    }
#pragma unroll
    for (int rt = 0; rt < 4; rt++) {
      int prow = rt * 16 + r;
      int chunk = ((m0 >> 3) + g) ^ (prow & 7);
      ar[rt] = *(const bf16x8*)&ShBuf[prow * 1024 + chunk * 8];
    }
    __builtin_amdgcn_s_setprio(1);
#pragma unroll
    for (int rt = 0; rt < 4; rt++)
#pragma unroll
      for (int bt = 0; bt < 2; bt++)
        o[rt][bt] = __builtin_amdgcn_mfma_f32_16x16x32_bf16(ar[rt], br[bt], o[rt][bt], 0, 0, 0);
    __builtin_amdgcn_s_setprio(0);
  }

  // ---- epilogue: direct packed stores; block covers full 128B line per c ----
  unsigned short* obase = QKVt + (long)b * NN * CC;
#pragma unroll
  for (int rt = 0; rt < 4; rt++) {
#pragma unroll
    for (int bt = 0; bt < 2; bt++) {
      int c = cw + bt * 16 + r;
      int n = n0 + rt * 16 + g * 4;
      s16x4 pk;
      pk.x = (short)f2bf(o[rt][bt][0]);
      pk.y = (short)f2bf(o[rt][bt][1]);
      pk.z = (short)f2bf(o[rt][bt][2]);
      pk.w = (short)f2bf(o[rt][bt][3]);
      *(s16x4*)(obase + (long)c * NN + n) = pk;
    }
  }
}

extern "C" void kernel_launch(void* const* d_in, const int* in_sizes, int n_in,
                              void* d_out, int out_size, void* d_ws, size_t ws_size,
                              hipStream_t stream) {
  const float* x  = (const float*)d_in[0];
  const float* Wq = (const float*)d_in[1];
  const float* bq = (const float*)d_in[2];
  const float* Wk = (const float*)d_in[3];
  const float* bk = (const float*)d_in[4];
  const float* Wv = (const float*)d_in[5];
  const float* bv = (const float*)d_in[6];
  const float* Wp = (const float*)d_in[7];
  float* out = (float*)d_out;

  const long BNC = (long)BB * NN * CC;

  char* p = (char*)d_ws;
  unsigned short* Amat  = (unsigned short*)p; p += (long)NN * NN * 2;
  unsigned short* Qb    = (unsigned short*)p; p += BNC * 2;
  unsigned short* Ktb   = (unsigned short*)p; p += BNC * 2;   // tiled Kt
  unsigned short* Vtb   = (unsigned short*)p; p += BNC * 2;   // tiled V5
  unsigned short* QKVt  = (unsigned short*)p; p += BNC * 2;   // [b][c][n]

  // Fused QKV projection (inline f32->bf16) + Wp transpose (z==6 slice)
  gemm_qkv<<<dim3(BB, 8, 7), 256, 0, stream>>>(
      x, Wq, Wk, Wv, bq, bk, bv, Wp, Qb, Ktb, Vtb, Amat);

  // Fused softmax(QK^T)·V -> QKVt[c][n];  64 rows/block, 8 waves, 1 block/CU
  attn_fused<<<dim3(BB, NN / 64), 512, 0, stream>>>(Qb, Ktb, Vtb, QKVt);

  // Z[hw][c] = sum_n Amat[hw][n] * QKVt[c][n] : M=1024, N=256, K=1024, f32 out
  gemm_tile<0, 1><<<dim3(BB, 8, 4), 256, 0, stream>>>(
      Amat, NN, 0L, QKVt, NN, (long)NN * CC, nullptr,
      out, CC, (long)NN * CC, NN);
}